// Round 1
// 231.866 us; speedup vs baseline: 1.1282x; 1.1282x over previous
//
#include <hip/hip_runtime.h>

typedef unsigned short u16;
typedef __bf16 bf16x8 __attribute__((ext_vector_type(8)));
typedef float f32x4 __attribute__((ext_vector_type(4)));

#define MFMA(a, b, c) __builtin_amdgcn_mfma_f32_16x16x32_bf16((a), (b), (c), 0, 0, 0)

__device__ __forceinline__ u16 f2bf(float f) {
    unsigned u = __float_as_uint(f);
    unsigned r = (u + 0x7fffu + ((u >> 16) & 1u)) >> 16;  // RNE
    return (u16)r;
}
__device__ __forceinline__ float bf2f(u16 h) { return __uint_as_float(((unsigned)h) << 16); }

typedef unsigned int u32_g __attribute__((address_space(1)));
typedef unsigned int u32_l __attribute__((address_space(3)));
__device__ __forceinline__ void gload16(const void* g, void* l) {
    // direct global->LDS DMA, 16B/lane; LDS dest = wave-uniform base + lane*16
    __builtin_amdgcn_global_load_lds((const u32_g*)g, (u32_l*)l, 16, 0, 0);
}

// ---------------------------------------------------------------------------
// Shapes: b=16, c=256, H=W=64 -> n=4096, heads=8, dim_head=32
// ---------------------------------------------------------------------------

// K1: fused LayerNorm + transpose: x (b,c,n) fp32 -> xlnT (b,n,c) bf16
__global__ __launch_bounds__(256) void k_ln(const float* __restrict__ x,
                                            const float* __restrict__ gamma,
                                            const float* __restrict__ beta,
                                            u16* __restrict__ xlnT) {
    int bid = blockIdx.x;
    int b = bid >> 6, nt = bid & 63;
    int nb = nt * 64;
    __shared__ unsigned xsu[256 * 33];
    __shared__ float muv[64], rsv[64];
    __shared__ float redS[8 * 64], redS2[8 * 64];
    int t = threadIdx.x;
    {
        int np = t & 31;
        int c0 = t >> 5;
        const float* xp = x + ((size_t)b * 256) * 4096 + nb + np * 2;
        for (int i = 0; i < 32; i++) {
            int c = c0 + i * 8;
            float2 f = *(const float2*)(xp + (size_t)c * 4096);
            unsigned u = (unsigned)f2bf(f.x) | ((unsigned)f2bf(f.y) << 16);
            xsu[c * 33 + np] = u;
        }
    }
    __syncthreads();
    {
        int np = t & 31, q = t >> 5;
        float s0 = 0, s20 = 0, s1 = 0, s21 = 0;
        for (int i = 0; i < 32; i++) {
            unsigned u = xsu[(q * 32 + i) * 33 + np];
            float a = bf2f((u16)(u & 0xffffu));
            float bv = bf2f((u16)(u >> 16));
            s0 += a; s20 += a * a; s1 += bv; s21 += bv * bv;
        }
        redS[q * 64 + np * 2] = s0;  redS[q * 64 + np * 2 + 1] = s1;
        redS2[q * 64 + np * 2] = s20; redS2[q * 64 + np * 2 + 1] = s21;
    }
    __syncthreads();
    if (t < 64) {
        float s = 0, s2 = 0;
        for (int q = 0; q < 8; q++) { s += redS[q * 64 + t]; s2 += redS2[q * 64 + t]; }
        float m = s * (1.f / 256.f);
        float var = s2 * (1.f / 256.f) - m * m;
        muv[t] = m;
        rsv[t] = rsqrtf(var + 1e-5f);
    }
    __syncthreads();
    {
        int c4 = (t & 63) * 4;
        int ng = t >> 6;
        float g[4], e[4];
        for (int j = 0; j < 4; j++) { g[j] = gamma[c4 + j]; e[j] = beta[c4 + j]; }
        for (int i = 0; i < 16; i++) {
            int n = ng * 16 + i;
            float m = muv[n], rs = rsv[n];
            u16 h[4];
            for (int j = 0; j < 4; j++) {
                unsigned u = xsu[(c4 + j) * 33 + (n >> 1)];
                u16 raw = (n & 1) ? (u16)(u >> 16) : (u16)(u & 0xffffu);
                float v = (bf2f(raw) - m) * rs * g[j] + e[j];
                h[j] = f2bf(v);
            }
            uint2 w2;
            w2.x = (unsigned)h[0] | ((unsigned)h[1] << 16);
            w2.y = (unsigned)h[2] | ((unsigned)h[3] << 16);
            *(uint2*)(xlnT + ((size_t)(b * 4096 + nb + n)) * 256 + c4) = w2;
        }
    }
}

// K2: weight transpose to bf16 + zero accumulators
__global__ __launch_bounds__(256) void k_prep(const float* __restrict__ Wqkv,
                                              const float* __restrict__ Wout,
                                              u16* __restrict__ WqkvT, u16* __restrict__ WoutT,
                                              float* __restrict__ sims, float* __restrict__ normsq) {
    int i = blockIdx.x * 256 + threadIdx.x;
    if (i < 768 * 256) { int o = i >> 8, c = i & 255; WqkvT[i] = f2bf(Wqkv[c * 768 + o]); }
    if (i < 256 * 256) { int o = i >> 8, c = i & 255; WoutT[i] = f2bf(Wout[c * 256 + o]); }
    if (i < 128 * 1024) sims[i] = 0.f;
    if (i < 16 * 512) normsq[i] = 0.f;
}

// K3: GEMM C[m][n] = A[m][0:256] . B^T[n][0:256], 128x128 tile, BK=32, 8 K-steps.
// Staging via global_load_lds (16B/lane), LDS linear [128][32] with bijective
// chunk-XOR swizzle: slot p of row r holds global k-chunk p ^ ((r>>1)&3).
// mode 0: q/k rows -> o16 bf16 (b,512,4096)
// mode 1: out rows + bias -> o32 fp32 (b,256,4096)
// mode 2: v rows, TRANSPOSING epilogue -> o16 = vT bf16 (b,4096,256)
__global__ __launch_bounds__(256) void k_gemm(const u16* __restrict__ A, size_t aStrB,
                                              const u16* __restrict__ Bb, size_t bStrB,
                                              int mtiles, int mrow0,
                                              u16* __restrict__ o16,
                                              float* __restrict__ o32, const float* __restrict__ bias,
                                              int mode) {
    extern __shared__ __align__(16) u16 smem[];
    u16* aT = smem;               // [128][32] linear, 8 KB
    u16* bT = smem + 128 * 32;    // [128][32] linear, 8 KB
    int bid = blockIdx.x;
    int per_b = mtiles * 32;
    int b = bid / per_b;
    int r2 = bid % per_b;
    int mbase = mrow0 + (r2 >> 5) * 128, nbase = (r2 & 31) * 128;
    int t = threadIdx.x, w = t >> 6, lane = t & 63, l15 = lane & 15, quad = lane >> 4;
    const u16* Ap = A + (size_t)b * aStrB;
    const u16* Bp = Bb + (size_t)b * bStrB;
    // staging: wave w covers rows w*32..w*32+31 of each tile in two 1KB calls.
    // lane -> row_local = 16grp + (lane>>2), slot chunk p = lane&3; global chunk = p ^ ((lane>>3)&3)
    int srow = lane >> 2;
    int g8 = (((lane & 3) ^ ((lane >> 3) & 3)) << 3);
    const u16* gA = Ap + (size_t)(mbase + w * 32 + srow) * 256 + g8;
    const u16* gB = Bp + (size_t)(nbase + w * 32 + srow) * 256 + g8;
    u16* lA = aT + w * 1024;
    u16* lB = bT + w * 1024;
    // fragment read: global chunk quad lives at LDS slot quad ^ ((row>>1)&3); for all rows
    // used below, (row>>1)&3 == (l15>>1)&3  (row bases are multiples of 16)
    int cOff = ((quad ^ ((l15 >> 1) & 3)) << 3);
    f32x4 acc[2][8];
    f32x4 z = {0.f, 0.f, 0.f, 0.f};
    for (int fm = 0; fm < 2; fm++)
        for (int fn = 0; fn < 8; fn++) acc[fm][fn] = z;
    for (int kt = 0; kt < 8; kt++) {
        int kb = kt * 32;
        if (kt) __syncthreads();
        gload16(gA + kb, lA);
        gload16(gA + 16 * 256 + kb, lA + 512);
        gload16(gB + kb, lB);
        gload16(gB + 16 * 256 + kb, lB + 512);
        __syncthreads();   // compiler drains vmcnt(0) here -> LDS ready
        bf16x8 af0 = *(const bf16x8*)&aT[(w * 32 + l15) * 32 + cOff];
        bf16x8 af1 = *(const bf16x8*)&aT[(w * 32 + 16 + l15) * 32 + cOff];
        for (int fn = 0; fn < 8; fn++) {
            bf16x8 bfr = *(const bf16x8*)&bT[(fn * 16 + l15) * 32 + cOff];
            acc[0][fn] = MFMA(af0, bfr, acc[0][fn]);
            acc[1][fn] = MFMA(af1, bfr, acc[1][fn]);
        }
    }
    if (mode == 0) {
        for (int fm = 0; fm < 2; fm++)
            for (int fn = 0; fn < 8; fn++)
                for (int r = 0; r < 4; r++) {
                    int row = mbase + w * 32 + fm * 16 + quad * 4 + r;
                    int col = nbase + fn * 16 + l15;
                    o16[((size_t)b * 512 + row) * 4096 + col] = f2bf(acc[fm][fn][r]);
                }
    } else if (mode == 1) {
        for (int fm = 0; fm < 2; fm++)
            for (int fn = 0; fn < 8; fn++)
                for (int r = 0; r < 4; r++) {
                    int row = mbase + w * 32 + fm * 16 + quad * 4 + r;
                    int col = nbase + fn * 16 + l15;
                    o32[((size_t)b * 256 + row) * 4096 + col] = acc[fm][fn][r] + bias[row];
                }
    } else {
        // mode 2: transpose 128x128 tile through LDS, write vT[b][n][j] coalesced
        __syncthreads();
        u16* tp = smem;  // [128 cols][136]
        for (int fm = 0; fm < 2; fm++)
            for (int fn = 0; fn < 8; fn++) {
                unsigned p01 = (unsigned)f2bf(acc[fm][fn][0]) | ((unsigned)f2bf(acc[fm][fn][1]) << 16);
                unsigned p23 = (unsigned)f2bf(acc[fm][fn][2]) | ((unsigned)f2bf(acc[fm][fn][3]) << 16);
                uint2 pk; pk.x = p01; pk.y = p23;
                *(uint2*)&tp[(fn * 16 + l15) * 136 + w * 32 + fm * 16 + quad * 4] = pk;
            }
        __syncthreads();
        int jb0 = mbase - 512;
        for (int p = 0; p < 8; p++) {
            int col = p * 16 + (t >> 4);
            int ch = t & 15;
            uint4 v = *(const uint4*)&tp[col * 136 + ch * 8];
            *(uint4*)(o16 + ((size_t)b * 4096 + nbase + col) * 256 + jb0 + ch * 8) = v;
        }
    }
}

// K4: raw sim = q.k^T over an n-chunk of 512 per block, fused per-row sum-of-squares.
// grid = 16*8*8 = 1024  (b, h, nsplit)
__global__ __launch_bounds__(256) void k_sim(const u16* __restrict__ qk, float* __restrict__ sims,
                                             float* __restrict__ normsq) {
    int bid = blockIdx.x;
    int ns = bid & 7, bh = bid >> 3;
    int b = bh >> 3, h = bh & 7;
    __shared__ u16 qs[32 * 264];
    __shared__ u16 ks[32 * 264];
    int t = threadIdx.x, w = t >> 6, lane = t & 63, l15 = lane & 15, quad = lane >> 4;
    int ib = w >> 1, jb = w & 1;
    const u16* qbase = qk + ((size_t)(b * 512) + h * 32) * 4096;
    const u16* kbase = qk + ((size_t)(b * 512) + 256 + h * 32) * 4096;
    int col8 = t & 31, rb = t >> 5;
    f32x4 acc = {0.f, 0.f, 0.f, 0.f};
    float sq[4] = {0.f, 0.f, 0.f, 0.f}, sk[4] = {0.f, 0.f, 0.f, 0.f};
    for (int kc = 0; kc < 2; kc++) {
        int kb = ns * 512 + kc * 256;
        if (kc) __syncthreads();
#pragma unroll
        for (int i = 0; i < 4; i++) {
            int r = rb + i * 8;
            uint4 pq = *(const uint4*)(qbase + (size_t)r * 4096 + kb + col8 * 8);
            *(uint4*)&qs[r * 264 + col8 * 8] = pq;
            const u16* us = (const u16*)&pq;
#pragma unroll
            for (int jj = 0; jj < 8; jj++) { float f = bf2f(us[jj]); sq[i] += f * f; }
            uint4 pk = *(const uint4*)(kbase + (size_t)r * 4096 + kb + col8 * 8);
            *(uint4*)&ks[r * 264 + col8 * 8] = pk;
            const u16* uk = (const u16*)&pk;
#pragma unroll
            for (int jj = 0; jj < 8; jj++) { float f = bf2f(uk[jj]); sk[i] += f * f; }
        }
        __syncthreads();
        for (int s = 0; s < 8; s++) {
            bf16x8 a = *(const bf16x8*)&qs[(ib * 16 + l15) * 264 + s * 32 + quad * 8];
            bf16x8 bb = *(const bf16x8*)&ks[(jb * 16 + l15) * 264 + s * 32 + quad * 8];
            acc = MFMA(a, bb, acc);
        }
    }
#pragma unroll
    for (int i = 0; i < 4; i++) {
#pragma unroll
        for (int m = 16; m >= 1; m >>= 1) {
            sq[i] += __shfl_xor(sq[i], m, 32);
            sk[i] += __shfl_xor(sk[i], m, 32);
        }
    }
    if (col8 == 0) {
#pragma unroll
        for (int i = 0; i < 4; i++) {
            atomicAdd(normsq + b * 512 + h * 32 + rb + i * 8, sq[i]);
            atomicAdd(normsq + b * 512 + 256 + h * 32 + rb + i * 8, sk[i]);
        }
    }
    float* sp = sims + (size_t)bh * 1024;
    for (int r = 0; r < 4; r++) {
        int row = ib * 16 + quad * 4 + r, col = jb * 16 + l15;
        atomicAdd(sp + row * 32 + col, acc[r]);
    }
}

// K5: softmax (fp32, in LDS) fused with M-build:  M[o][h*32+j] = sum_d WoutT[o][h*32+d]*attn[d][j]
// grid = 128 (b*8+h), block 256
__global__ __launch_bounds__(256) void k_softmw(const float* __restrict__ sims,
                                                const float* __restrict__ normsq,
                                                const float* __restrict__ temp,
                                                const u16* __restrict__ WoutT,
                                                u16* __restrict__ Mb) {
    int bh = blockIdx.x;
    int b = bh >> 3, h = bh & 7;
    __shared__ float as[32 * 32];
    __shared__ float scq[32], sck[32];
    int t = threadIdx.x;
    if (t < 32)
        scq[t] = expf(temp[h]) * 8.0f / fmaxf(sqrtf(normsq[b * 512 + h * 32 + t]), 1e-12f);
    else if (t < 64) {
        int d = t - 32;
        sck[d] = 1.0f / fmaxf(sqrtf(normsq[b * 512 + 256 + h * 32 + d]), 1e-12f);
    }
    __syncthreads();
    if (t < 32) {
        float row[32];
        float m = -1e30f;
        const float* sp = sims + (size_t)bh * 1024 + t * 32;
        float sq = scq[t];
#pragma unroll
        for (int j = 0; j < 32; j++) { float v = sp[j] * sq * sck[j]; row[j] = v; m = fmaxf(m, v); }
        float s = 0.f;
#pragma unroll
        for (int j = 0; j < 32; j++) { float p = expf(row[j] - m); row[j] = p; s += p; }
        float inv = 1.f / s;
#pragma unroll
        for (int j = 0; j < 32; j++) as[t * 32 + j] = row[j] * inv;
    }
    __syncthreads();
    float wv[32];
    const u16* wp = WoutT + (size_t)t * 256 + h * 32;
#pragma unroll
    for (int d = 0; d < 32; d++) wv[d] = bf2f(wp[d]);
    u16* mp = Mb + ((size_t)b * 256 + t) * 256 + h * 32;
    for (int j0 = 0; j0 < 32; j0 += 8) {
        u16 hh[8];
#pragma unroll
        for (int jj = 0; jj < 8; jj++) {
            int j = j0 + jj;
            float s = 0.f;
#pragma unroll
            for (int d = 0; d < 32; d++) s += wv[d] * as[d * 32 + j];
            hh[jj] = f2bf(s);
        }
        uint4 pk;
        pk.x = (unsigned)hh[0] | ((unsigned)hh[1] << 16);
        pk.y = (unsigned)hh[2] | ((unsigned)hh[3] << 16);
        pk.z = (unsigned)hh[4] | ((unsigned)hh[5] << 16);
        pk.w = (unsigned)hh[6] | ((unsigned)hh[7] << 16);
        *(uint4*)(mp + j0) = pk;
    }
}

extern "C" void kernel_launch(void* const* d_in, const int* in_sizes, int n_in,
                              void* d_out, int out_size, void* d_ws, size_t ws_size,
                              hipStream_t stream) {
    const float* x     = (const float*)d_in[0];
    const float* gamma = (const float*)d_in[1];
    const float* beta  = (const float*)d_in[2];
    const float* Wqkv  = (const float*)d_in[3];
    const float* temp  = (const float*)d_in[4];
    const float* Wout  = (const float*)d_in[5];
    const float* bout  = (const float*)d_in[6];
    float* out = (float*)d_out;

    char* ws = (char*)d_ws;
    size_t off = 0;
    auto alloc = [&](size_t nbytes) -> void* {
        void* p = ws + off;
        off = (off + nbytes + 255) & ~(size_t)255;
        return p;
    };
    u16* xlnT    = (u16*)alloc((size_t)16 * 4096 * 256 * 2);  // 32 MB (b,n,c)
    u16* WqkvT   = (u16*)alloc((size_t)768 * 256 * 2);
    u16* WoutT   = (u16*)alloc((size_t)256 * 256 * 2);
    u16* qk      = (u16*)alloc((size_t)16 * 512 * 4096 * 2);  // 64 MB (b,o<512,n)
    u16* vT      = (u16*)alloc((size_t)16 * 4096 * 256 * 2);  // 32 MB (b,n,j)
    u16* Mb      = (u16*)alloc((size_t)16 * 256 * 256 * 2);   // 2 MB fused attn*Wout
    float* normsq = (float*)alloc((size_t)16 * 512 * 4);
    float* sims   = (float*)alloc((size_t)128 * 1024 * 4);
    (void)ws_size; (void)in_sizes; (void)n_in; (void)out_size;

    hipLaunchKernelGGL(k_ln, dim3(1024), dim3(256), 0, stream, x, gamma, beta, xlnT);
    hipLaunchKernelGGL(k_prep, dim3(768), dim3(256), 0, stream, Wqkv, Wout, WqkvT, WoutT, sims, normsq);
    // q/k rows (0..511)
    hipLaunchKernelGGL(k_gemm, dim3(2048), dim3(256), 16384, stream,
                       WqkvT, (size_t)0, xlnT, (size_t)4096 * 256, 4, 0,
                       qk, (float*)nullptr, (const float*)nullptr, 0);
    // v rows (512..767) -> transposed vT
    hipLaunchKernelGGL(k_gemm, dim3(1024), dim3(256), 34816, stream,
                       WqkvT, (size_t)0, xlnT, (size_t)4096 * 256, 2, 512,
                       vT, (float*)nullptr, (const float*)nullptr, 2);
    hipLaunchKernelGGL(k_sim, dim3(1024), dim3(256), 0, stream, qk, sims, normsq);
    hipLaunchKernelGGL(k_softmw, dim3(128), dim3(256), 0, stream, sims, normsq, temp, WoutT, Mb);
    // out = M . v  (+bias), consumes vT in the standard B^T layout
    hipLaunchKernelGGL(k_gemm, dim3(1024), dim3(256), 16384, stream,
                       Mb, (size_t)256 * 256, vT, (size_t)4096 * 256, 2, 0,
                       (u16*)nullptr, out, bout, 1);
}

// Round 3
// 218.737 us; speedup vs baseline: 1.1959x; 1.0600x over previous
//
#include <hip/hip_runtime.h>

typedef unsigned short u16;
typedef __bf16 bf16x8 __attribute__((ext_vector_type(8)));
typedef float f32x4 __attribute__((ext_vector_type(4)));

#define MFMA(a, b, c) __builtin_amdgcn_mfma_f32_16x16x32_bf16((a), (b), (c), 0, 0, 0)

__device__ __forceinline__ u16 f2bf(float f) {
    unsigned u = __float_as_uint(f);
    unsigned r = (u + 0x7fffu + ((u >> 16) & 1u)) >> 16;  // RNE
    return (u16)r;
}
__device__ __forceinline__ float bf2f(u16 h) { return __uint_as_float(((unsigned)h) << 16); }

typedef unsigned int u32_g __attribute__((address_space(1)));
typedef unsigned int u32_l __attribute__((address_space(3)));
__device__ __forceinline__ void gload16(const void* g, void* l) {
    __builtin_amdgcn_global_load_lds((const u32_g*)g, (u32_l*)l, 16, 0, 0);
}

// ---------------------------------------------------------------------------
// Shapes: b=16, c=256, n=4096, heads=8, dim_head=32
// Gram-trick pipeline: everything n-sized collapses through G = X.X^T (256x256/b)
// ---------------------------------------------------------------------------

// K1: LayerNorm. x (b,c,n) fp32 -> xlnT (b,n,c) bf16  AND  xcn (b,c,n) bf16
__global__ __launch_bounds__(256) void k_ln(const float* __restrict__ x,
                                            const float* __restrict__ gamma,
                                            const float* __restrict__ beta,
                                            u16* __restrict__ xlnT, u16* __restrict__ xcn) {
    int bid = blockIdx.x;
    int b = bid >> 6, nt = bid & 63;
    int nb = nt * 64;
    __shared__ unsigned xsu[256 * 33];
    __shared__ float muv[64], rsv[64];
    __shared__ float redS[8 * 64], redS2[8 * 64];
    int t = threadIdx.x;
    {
        int np = t & 31;
        int c0 = t >> 5;
        const float* xp = x + ((size_t)b * 256) * 4096 + nb + np * 2;
        for (int i = 0; i < 32; i++) {
            int c = c0 + i * 8;
            float2 f = *(const float2*)(xp + (size_t)c * 4096);
            unsigned u = (unsigned)f2bf(f.x) | ((unsigned)f2bf(f.y) << 16);
            xsu[c * 33 + np] = u;
        }
    }
    __syncthreads();
    {
        int np = t & 31, q = t >> 5;
        float s0 = 0, s20 = 0, s1 = 0, s21 = 0;
        for (int i = 0; i < 32; i++) {
            unsigned u = xsu[(q * 32 + i) * 33 + np];
            float a = bf2f((u16)(u & 0xffffu));
            float bv = bf2f((u16)(u >> 16));
            s0 += a; s20 += a * a; s1 += bv; s21 += bv * bv;
        }
        redS[q * 64 + np * 2] = s0;  redS[q * 64 + np * 2 + 1] = s1;
        redS2[q * 64 + np * 2] = s20; redS2[q * 64 + np * 2 + 1] = s21;
    }
    __syncthreads();
    if (t < 64) {
        float s = 0, s2 = 0;
        for (int q = 0; q < 8; q++) { s += redS[q * 64 + t]; s2 += redS2[q * 64 + t]; }
        float m = s * (1.f / 256.f);
        float var = s2 * (1.f / 256.f) - m * m;
        muv[t] = m;
        rsv[t] = rsqrtf(var + 1e-5f);
    }
    __syncthreads();
    // phase 3: xlnT[b][n][c]
    {
        int c4 = (t & 63) * 4;
        int ng = t >> 6;
        float g[4], e[4];
        for (int j = 0; j < 4; j++) { g[j] = gamma[c4 + j]; e[j] = beta[c4 + j]; }
        for (int i = 0; i < 16; i++) {
            int n = ng * 16 + i;
            float m = muv[n], rs = rsv[n];
            u16 h[4];
            for (int j = 0; j < 4; j++) {
                unsigned u = xsu[(c4 + j) * 33 + (n >> 1)];
                u16 raw = (n & 1) ? (u16)(u >> 16) : (u16)(u & 0xffffu);
                float v = (bf2f(raw) - m) * rs * g[j] + e[j];
                h[j] = f2bf(v);
            }
            uint2 w2;
            w2.x = (unsigned)h[0] | ((unsigned)h[1] << 16);
            w2.y = (unsigned)h[2] | ((unsigned)h[3] << 16);
            *(uint2*)(xlnT + ((size_t)(b * 4096 + nb + n)) * 256 + c4) = w2;
        }
    }
    // phase 4: xcn[b][c][n]
    {
        int lr = t & 7;
        int n0 = lr * 8;
        for (int it = 0; it < 8; it++) {
            int cg = (t >> 3) + it * 32;
            float g = gamma[cg], e = beta[cg];
            u16 hh[8];
            for (int jj = 0; jj < 8; jj++) {
                int nn = n0 + jj;
                unsigned u = xsu[cg * 33 + (nn >> 1)];
                u16 raw = (nn & 1) ? (u16)(u >> 16) : (u16)(u & 0xffffu);
                float v = (bf2f(raw) - muv[nn]) * rsv[nn] * g + e;
                hh[jj] = f2bf(v);
            }
            uint4 pk;
            pk.x = (unsigned)hh[0] | ((unsigned)hh[1] << 16);
            pk.y = (unsigned)hh[2] | ((unsigned)hh[3] << 16);
            pk.z = (unsigned)hh[4] | ((unsigned)hh[5] << 16);
            pk.w = (unsigned)hh[6] | ((unsigned)hh[7] << 16);
            *(uint4*)(xcn + ((size_t)(b * 256 + cg)) * 4096 + nb + n0) = pk;
        }
    }
}

// K2: weight prep. WqkvT[o<512][c]=Wqkv[c][o]; WvTn[c][o]=Wqkv[c][512+o]; WoutT[e][o]=Wout[o][e]
__global__ __launch_bounds__(256) void k_prep(const float* __restrict__ Wqkv,
                                              const float* __restrict__ Wout,
                                              u16* __restrict__ WqkvT, u16* __restrict__ WvTn,
                                              u16* __restrict__ WoutT) {
    int i = blockIdx.x * 256 + threadIdx.x;
    if (i < 512 * 256) { int o = i >> 8, c = i & 255; WqkvT[i] = f2bf(Wqkv[c * 768 + o]); }
    if (i < 256 * 256) {
        int e = i >> 8, o = i & 255;
        WvTn[i] = f2bf(Wqkv[e * 768 + 512 + o]);
        WoutT[i] = f2bf(Wout[o * 256 + e]);
    }
}

// K3: Gram partials. Gp[s][b] = X[tm-panel] . X[tn-panel]^T over n in [s*512, s*512+512)
__global__ __launch_bounds__(256) void k_gram(const u16* __restrict__ xcn, float* __restrict__ Gp) {
    int bid = blockIdx.x;
    int s = bid & 7, tile = (bid >> 3) & 3, b = bid >> 5;
    int tm = tile >> 1, tn = tile & 1;
    __shared__ __align__(16) u16 aT[128 * 32];
    __shared__ __align__(16) u16 bT[128 * 32];
    int t = threadIdx.x, w = t >> 6, lane = t & 63, l15 = lane & 15, quad = lane >> 4;
    int srow = lane >> 2;
    int g8 = (((lane & 3) ^ ((lane >> 3) & 3)) << 3);
    const u16* xb = xcn + (size_t)b * 256 * 4096 + (size_t)s * 512;
    const u16* gA = xb + (size_t)(tm * 128 + w * 32 + srow) * 4096 + g8;
    const u16* gB = xb + (size_t)(tn * 128 + w * 32 + srow) * 4096 + g8;
    u16* lA = aT + w * 1024;
    u16* lB = bT + w * 1024;
    int cOff = ((quad ^ ((l15 >> 1) & 3)) << 3);
    f32x4 acc[2][8];
    f32x4 z = {0.f, 0.f, 0.f, 0.f};
    for (int fm = 0; fm < 2; fm++)
        for (int fn = 0; fn < 8; fn++) acc[fm][fn] = z;
    for (int kt = 0; kt < 16; kt++) {
        int kb = kt * 32;
        if (kt) __syncthreads();
        gload16(gA + kb, lA);
        gload16(gA + 16 * 4096 + kb, lA + 512);
        gload16(gB + kb, lB);
        gload16(gB + 16 * 4096 + kb, lB + 512);
        __syncthreads();
        bf16x8 af0 = *(const bf16x8*)&aT[(w * 32 + l15) * 32 + cOff];
        bf16x8 af1 = *(const bf16x8*)&aT[(w * 32 + 16 + l15) * 32 + cOff];
        for (int fn = 0; fn < 8; fn++) {
            bf16x8 bfr = *(const bf16x8*)&bT[(fn * 16 + l15) * 32 + cOff];
            acc[0][fn] = MFMA(af0, bfr, acc[0][fn]);
            acc[1][fn] = MFMA(af1, bfr, acc[1][fn]);
        }
    }
    float* gp = Gp + (size_t)(s * 16 + b) * 65536;
    for (int fm = 0; fm < 2; fm++)
        for (int fn = 0; fn < 8; fn++)
            for (int r = 0; r < 4; r++) {
                int row = tm * 128 + w * 32 + fm * 16 + quad * 4 + r;
                int col = tn * 128 + fn * 16 + l15;
                gp[row * 256 + col] = acc[fm][fn][r];
            }
}

// K4: G = sum of 8 partials -> hi/lo bf16 split (Ghi + Glo ~= G fp32)
__global__ __launch_bounds__(256) void k_g2b(const float* __restrict__ Gp,
                                             u16* __restrict__ Ghi, u16* __restrict__ Glo) {
    int idx = blockIdx.x * 256 + threadIdx.x;  // < 262144 float4s
    const float4* p = (const float4*)Gp + idx;
    float4 s = p[0];
#pragma unroll
    for (int j = 1; j < 8; j++) {
        float4 v = p[(size_t)j * 262144];
        s.x += v.x; s.y += v.y; s.z += v.z; s.w += v.w;
    }
    u16 h0 = f2bf(s.x), h1 = f2bf(s.y), h2 = f2bf(s.z), h3 = f2bf(s.w);
    u16 l0 = f2bf(s.x - bf2f(h0)), l1 = f2bf(s.y - bf2f(h1));
    u16 l2 = f2bf(s.z - bf2f(h2)), l3 = f2bf(s.w - bf2f(h3));
    uint2 ph; ph.x = (unsigned)h0 | ((unsigned)h1 << 16); ph.y = (unsigned)h2 | ((unsigned)h3 << 16);
    uint2 pl; pl.x = (unsigned)l0 | ((unsigned)l1 << 16); pl.y = (unsigned)l2 | ((unsigned)l3 << 16);
    *(uint2*)(Ghi + (size_t)idx * 4) = ph;
    *(uint2*)(Glo + (size_t)idx * 4) = pl;
}

// K5: Sq = Wqk (512x256) . (Ghi + Glo), hi/lo output. grid = 16*8 = 128
__global__ __launch_bounds__(256) void k_sq(const u16* __restrict__ A,
                                            const u16* __restrict__ Ghi, const u16* __restrict__ Glo,
                                            u16* __restrict__ Shi, u16* __restrict__ Slo) {
    __shared__ __align__(16) u16 aT[128 * 32];
    __shared__ __align__(16) u16 bT[128 * 32];
    int bid = blockIdx.x;
    int b = bid >> 3;
    int r2 = bid & 7;
    int mbase = (r2 >> 1) * 128, nbase = (r2 & 1) * 128;
    int t = threadIdx.x, w = t >> 6, lane = t & 63, l15 = lane & 15, quad = lane >> 4;
    int srow = lane >> 2;
    int g8 = (((lane & 3) ^ ((lane >> 3) & 3)) << 3);
    const u16* gA = A + (size_t)(mbase + w * 32 + srow) * 256 + g8;
    const u16* gBh = Ghi + (size_t)b * 65536 + (size_t)(nbase + w * 32 + srow) * 256 + g8;
    const u16* gBl = Glo + (size_t)b * 65536 + (size_t)(nbase + w * 32 + srow) * 256 + g8;
    u16* lA = aT + w * 1024;
    u16* lB = bT + w * 1024;
    int cOff = ((quad ^ ((l15 >> 1) & 3)) << 3);
    f32x4 acc[2][8];
    f32x4 z = {0.f, 0.f, 0.f, 0.f};
    for (int fm = 0; fm < 2; fm++)
        for (int fn = 0; fn < 8; fn++) acc[fm][fn] = z;
    for (int kt = 0; kt < 16; kt++) {
        int kb = (kt & 7) * 32;
        const u16* gB = (kt < 8) ? gBh : gBl;
        if (kt) __syncthreads();
        gload16(gA + kb, lA);
        gload16(gA + 16 * 256 + kb, lA + 512);
        gload16(gB + kb, lB);
        gload16(gB + 16 * 256 + kb, lB + 512);
        __syncthreads();
        bf16x8 af0 = *(const bf16x8*)&aT[(w * 32 + l15) * 32 + cOff];
        bf16x8 af1 = *(const bf16x8*)&aT[(w * 32 + 16 + l15) * 32 + cOff];
        for (int fn = 0; fn < 8; fn++) {
            bf16x8 bfr = *(const bf16x8*)&bT[(fn * 16 + l15) * 32 + cOff];
            acc[0][fn] = MFMA(af0, bfr, acc[0][fn]);
            acc[1][fn] = MFMA(af1, bfr, acc[1][fn]);
        }
    }
    for (int fm = 0; fm < 2; fm++)
        for (int fn = 0; fn < 8; fn++)
            for (int r = 0; r < 4; r++) {
                int row = mbase + w * 32 + fm * 16 + quad * 4 + r;
                int col = nbase + fn * 16 + l15;
                float v = acc[fm][fn][r];
                u16 hi = f2bf(v);
                Shi[((size_t)b * 512 + row) * 256 + col] = hi;
                Slo[((size_t)b * 512 + row) * 256 + col] = f2bf(v - bf2f(hi));
            }
}

// K6: generic 128x128-tile GEMM, K=256: C[m][col] = sum_k A[m][k]*B[col][k]
// mode 0: bf16 out; mode 1: fp32 + bias
__global__ __launch_bounds__(256) void k_gemm(const u16* __restrict__ A, size_t aStrB,
                                              const u16* __restrict__ Bb, size_t bStrB,
                                              int mtiles, int ntiles,
                                              u16* __restrict__ o16, float* __restrict__ o32,
                                              const float* __restrict__ bias,
                                              size_t oStrB, int oRstr, int mode) {
    __shared__ __align__(16) u16 aT[128 * 32];
    __shared__ __align__(16) u16 bT[128 * 32];
    int bid = blockIdx.x;
    int per_b = mtiles * ntiles;
    int b = bid / per_b;
    int r2 = bid % per_b;
    int mbase = (r2 / ntiles) * 128, nbase = (r2 % ntiles) * 128;
    int t = threadIdx.x, w = t >> 6, lane = t & 63, l15 = lane & 15, quad = lane >> 4;
    const u16* Ap = A + (size_t)b * aStrB;
    const u16* Bp = Bb + (size_t)b * bStrB;
    int srow = lane >> 2;
    int g8 = (((lane & 3) ^ ((lane >> 3) & 3)) << 3);
    const u16* gA = Ap + (size_t)(mbase + w * 32 + srow) * 256 + g8;
    const u16* gB = Bp + (size_t)(nbase + w * 32 + srow) * 256 + g8;
    u16* lA = aT + w * 1024;
    u16* lB = bT + w * 1024;
    int cOff = ((quad ^ ((l15 >> 1) & 3)) << 3);
    f32x4 acc[2][8];
    f32x4 z = {0.f, 0.f, 0.f, 0.f};
    for (int fm = 0; fm < 2; fm++)
        for (int fn = 0; fn < 8; fn++) acc[fm][fn] = z;
    for (int kt = 0; kt < 8; kt++) {
        int kb = kt * 32;
        if (kt) __syncthreads();
        gload16(gA + kb, lA);
        gload16(gA + 16 * 256 + kb, lA + 512);
        gload16(gB + kb, lB);
        gload16(gB + 16 * 256 + kb, lB + 512);
        __syncthreads();
        bf16x8 af0 = *(const bf16x8*)&aT[(w * 32 + l15) * 32 + cOff];
        bf16x8 af1 = *(const bf16x8*)&aT[(w * 32 + 16 + l15) * 32 + cOff];
        for (int fn = 0; fn < 8; fn++) {
            bf16x8 bfr = *(const bf16x8*)&bT[(fn * 16 + l15) * 32 + cOff];
            acc[0][fn] = MFMA(af0, bfr, acc[0][fn]);
            acc[1][fn] = MFMA(af1, bfr, acc[1][fn]);
        }
    }
    if (mode == 0) {
        for (int fm = 0; fm < 2; fm++)
            for (int fn = 0; fn < 8; fn++)
                for (int r = 0; r < 4; r++) {
                    int row = mbase + w * 32 + fm * 16 + quad * 4 + r;
                    int col = nbase + fn * 16 + l15;
                    o16[(size_t)b * oStrB + (size_t)row * oRstr + col] = f2bf(acc[fm][fn][r]);
                }
    } else {
        for (int fm = 0; fm < 2; fm++)
            for (int fn = 0; fn < 8; fn++)
                for (int r = 0; r < 4; r++) {
                    int row = mbase + w * 32 + fm * 16 + quad * 4 + r;
                    int col = nbase + fn * 16 + l15;
                    o32[(size_t)b * oStrB + (size_t)row * oRstr + col] = acc[fm][fn][r] + bias[row];
                }
    }
}

// K7: per (b,h): sim = (Sq_hi+Sq_lo) . Wk^T (MFMA), norms from diag, softmax, M_h = wo.attn
// grid = 128 (b*8+h), block 256
__global__ __launch_bounds__(256) void k_attn(const u16* __restrict__ Shi,
                                              const u16* __restrict__ Slo,
                                              const u16* __restrict__ WqkvT,
                                              const u16* __restrict__ WoutT,
                                              const float* __restrict__ temp,
                                              u16* __restrict__ M_all) {
    int bh = blockIdx.x;
    int b = bh >> 3, h = bh & 7;
    __shared__ u16 sqh[32 * 264], sql[32 * 264], skh[32 * 264], wq[32 * 264], wk[32 * 264];
    __shared__ u16 wo[256 * 40];
    __shared__ u16 attnT[32 * 40];
    __shared__ float simS[32 * 33];
    __shared__ float redn[4 * 64];
    __shared__ float scq[32], sck[32];
    int t = threadIdx.x, w = t >> 6, lane = t & 63, l15 = lane & 15, quad = lane >> 4;
    {
        int r = t >> 3, cc0 = (t & 7) * 32;
        const u16* gqh = Shi + ((size_t)(b * 512) + h * 32 + r) * 256 + cc0;
        const u16* gql = Slo + ((size_t)(b * 512) + h * 32 + r) * 256 + cc0;
        const u16* gkh = Shi + ((size_t)(b * 512) + 256 + h * 32 + r) * 256 + cc0;
        const u16* gwq = WqkvT + (size_t)(h * 32 + r) * 256 + cc0;
        const u16* gwk = WqkvT + (size_t)(256 + h * 32 + r) * 256 + cc0;
#pragma unroll
        for (int k = 0; k < 4; k++) {
            *(uint4*)&sqh[r * 264 + cc0 + k * 8] = *(const uint4*)(gqh + k * 8);
            *(uint4*)&sql[r * 264 + cc0 + k * 8] = *(const uint4*)(gql + k * 8);
            *(uint4*)&skh[r * 264 + cc0 + k * 8] = *(const uint4*)(gkh + k * 8);
            *(uint4*)&wq[r * 264 + cc0 + k * 8] = *(const uint4*)(gwq + k * 8);
            *(uint4*)&wk[r * 264 + cc0 + k * 8] = *(const uint4*)(gwk + k * 8);
        }
        const u16* gwo = WoutT + (size_t)t * 256 + h * 32;
#pragma unroll
        for (int k = 0; k < 4; k++) *(uint4*)&wo[t * 40 + k * 8] = *(const uint4*)(gwo + k * 8);
    }
    __syncthreads();
    // norms: |q_i|^2 = (Wq G)[i].Wq[i] ; |k_j|^2 = (Wk G)[j].Wk[j]
    {
        int rn = t & 63, cc = t >> 6;
        int e0 = cc * 64;
        float s = 0.f;
        if (rn < 32) {
            const u16* ph = &sqh[rn * 264];
            const u16* pl = &sql[rn * 264];
            const u16* pb = &wq[rn * 264];
            for (int e = 0; e < 64; e++)
                s += (bf2f(ph[e0 + e]) + bf2f(pl[e0 + e])) * bf2f(pb[e0 + e]);
        } else {
            const u16* ph = &skh[(rn - 32) * 264];
            const u16* pb = &wk[(rn - 32) * 264];
            for (int e = 0; e < 64; e++)
                s += bf2f(ph[e0 + e]) * bf2f(pb[e0 + e]);
        }
        redn[cc * 64 + rn] = s;
    }
    // sim MFMA: A = Sq rows (hi then lo), B = Wk WEIGHT rows  -> sim = Wq.G.Wk^T
    {
        int iq = w >> 1, jq = w & 1;
        f32x4 acc = {0.f, 0.f, 0.f, 0.f};
        for (int s8 = 0; s8 < 8; s8++) {
            bf16x8 a = *(const bf16x8*)&sqh[(iq * 16 + l15) * 264 + s8 * 32 + quad * 8];
            bf16x8 bb = *(const bf16x8*)&wk[(jq * 16 + l15) * 264 + s8 * 32 + quad * 8];
            acc = MFMA(a, bb, acc);
        }
        for (int s8 = 0; s8 < 8; s8++) {
            bf16x8 a = *(const bf16x8*)&sql[(iq * 16 + l15) * 264 + s8 * 32 + quad * 8];
            bf16x8 bb = *(const bf16x8*)&wk[(jq * 16 + l15) * 264 + s8 * 32 + quad * 8];
            acc = MFMA(a, bb, acc);
        }
        for (int r = 0; r < 4; r++)
            simS[(iq * 16 + quad * 4 + r) * 33 + jq * 16 + l15] = acc[r];
    }
    __syncthreads();
    if (t < 32)
        scq[t] = expf(temp[h]) * 8.0f /
                 fmaxf(sqrtf(redn[t] + redn[64 + t] + redn[128 + t] + redn[192 + t]), 1e-12f);
    else if (t < 64) {
        int d = t - 32;
        sck[d] = 1.0f / fmaxf(sqrtf(redn[32 + d] + redn[96 + d] + redn[160 + d] + redn[224 + d]), 1e-12f);
    }
    __syncthreads();
    if (t < 32) {
        float row[32];
        float m = -1e30f, sqv = scq[t];
#pragma unroll
        for (int j = 0; j < 32; j++) {
            float v = simS[t * 33 + j] * sqv * sck[j];
            row[j] = v; m = fmaxf(m, v);
        }
        float s = 0.f;
#pragma unroll
        for (int j = 0; j < 32; j++) { float p = expf(row[j] - m); row[j] = p; s += p; }
        float inv = 1.f / s;
#pragma unroll
        for (int j = 0; j < 32; j++) attnT[j * 40 + t] = f2bf(row[j] * inv);  // attnT[j][i]
    }
    __syncthreads();
    // M_h[c][j] = sum_d wo[c][d] attn[d][j]
    {
        f32x4 z = {0.f, 0.f, 0.f, 0.f};
        for (int mf = 0; mf < 4; mf++) {
            bf16x8 a = *(const bf16x8*)&wo[((w * 4 + mf) * 16 + l15) * 40 + quad * 8];
            for (int nf = 0; nf < 2; nf++) {
                bf16x8 bb = *(const bf16x8*)&attnT[(nf * 16 + l15) * 40 + quad * 8];
                f32x4 d = MFMA(a, bb, z);
                for (int r = 0; r < 4; r++) {
                    int c = (w * 4 + mf) * 16 + quad * 4 + r;
                    M_all[((size_t)(b * 256) + c) * 256 + h * 32 + nf * 16 + l15] = f2bf(d[r]);
                }
            }
        }
    }
}

extern "C" void kernel_launch(void* const* d_in, const int* in_sizes, int n_in,
                              void* d_out, int out_size, void* d_ws, size_t ws_size,
                              hipStream_t stream) {
    const float* x     = (const float*)d_in[0];
    const float* gamma = (const float*)d_in[1];
    const float* beta  = (const float*)d_in[2];
    const float* Wqkv  = (const float*)d_in[3];
    const float* temp  = (const float*)d_in[4];
    const float* Wout  = (const float*)d_in[5];
    const float* bout  = (const float*)d_in[6];
    float* out = (float*)d_out;

    char* ws = (char*)d_ws;
    size_t off = 0;
    auto alloc = [&](size_t nbytes) -> void* {
        void* p = ws + off;
        off = (off + nbytes + 255) & ~(size_t)255;
        return p;
    };
    u16* xlnT   = (u16*)alloc((size_t)16 * 4096 * 256 * 2);   // 32 MB (b,n,c)
    u16* xcn    = (u16*)alloc((size_t)16 * 256 * 4096 * 2);   // 32 MB (b,c,n)
    u16* WqkvT  = (u16*)alloc((size_t)512 * 256 * 2);
    u16* WvTn   = (u16*)alloc((size_t)256 * 256 * 2);
    u16* WoutT  = (u16*)alloc((size_t)256 * 256 * 2);
    float* Gp   = (float*)alloc((size_t)8 * 16 * 65536 * 4);  // 32 MB
    u16* Gbh    = (u16*)alloc((size_t)16 * 65536 * 2);        // 2 MB
    u16* Gbl    = (u16*)alloc((size_t)16 * 65536 * 2);        // 2 MB
    u16* Sqh    = (u16*)alloc((size_t)16 * 512 * 256 * 2);    // 4 MB
    u16* Sql    = (u16*)alloc((size_t)16 * 512 * 256 * 2);    // 4 MB
    u16* M_all  = (u16*)alloc((size_t)16 * 256 * 256 * 2);    // 2 MB
    u16* F      = (u16*)alloc((size_t)16 * 256 * 256 * 2);    // 2 MB
    (void)ws_size; (void)in_sizes; (void)n_in; (void)out_size;

    hipLaunchKernelGGL(k_ln, dim3(1024), dim3(256), 0, stream, x, gamma, beta, xlnT, xcn);
    hipLaunchKernelGGL(k_prep, dim3(768), dim3(256), 0, stream, Wqkv, Wout, WqkvT, WvTn, WoutT);
    hipLaunchKernelGGL(k_gram, dim3(512), dim3(256), 0, stream, xcn, Gp);
    hipLaunchKernelGGL(k_g2b, dim3(1024), dim3(256), 0, stream, Gp, Gbh, Gbl);
    hipLaunchKernelGGL(k_sq, dim3(128), dim3(256), 0, stream, WqkvT, Gbh, Gbl, Sqh, Sql);
    hipLaunchKernelGGL(k_attn, dim3(128), dim3(256), 0, stream, Sqh, Sql, WqkvT, WoutT, temp, M_all);
    // F[b] = M_b (256x256) . Wv  (B-rows = WvTn rows, i.e. F = M.Wv^T in hj)
    hipLaunchKernelGGL(k_gemm, dim3(64), dim3(256), 0, stream,
                       M_all, (size_t)65536, WvTn, (size_t)0, 2, 2,
                       F, (float*)nullptr, (const float*)nullptr,
                       (size_t)65536, 256, 0);
    // out[b] = F_b (256x256) . X_b  (+bias): B-rows = xlnT rows (n,c)
    hipLaunchKernelGGL(k_gemm, dim3(1024), dim3(256), 0, stream,
                       F, (size_t)65536, xlnT, (size_t)4096 * 256, 2, 32,
                       (u16*)nullptr, out, bout,
                       (size_t)256 * 4096, 4096, 1);
}